// Round 1
// baseline (175.641 us; speedup 1.0000x reference)
//
#include <hip/hip_runtime.h>
#include <hip/hip_bf16.h>

typedef unsigned short u16;
typedef __attribute__((ext_vector_type(4))) float f32x4;
typedef __attribute__((ext_vector_type(8))) short bf16x8;

#define IN_F   4096
#define OUT_F  4096
#define BATCH  512

#define BM 64
#define BN 128
#define BK 64

__device__ inline u16 f2bf(float f) {
    __hip_bfloat16 h = __float2bfloat16(f);   // RNE
    u16 u; __builtin_memcpy(&u, &h, 2); return u;
}

// Pass 1: last-write-wins index resolution. aux must be pre-set to -1 (memset 0xFF).
__global__ __launch_bounds__(256) void scatter_max(const int* __restrict__ row,
                                                   const int* __restrict__ col,
                                                   int* __restrict__ aux, int nnz) {
    int i = blockIdx.x * 256 + threadIdx.x;
    if (i < nnz) {
        int pos = row[i] * IN_F + col[i];
        atomicMax(&aux[pos], i);
    }
}

// Pass 2: build dense bf16 W (zero-fill fused with scatter resolution).
__global__ __launch_bounds__(256) void fill_w(const int* __restrict__ aux,
                                              const float* __restrict__ w,
                                              u16* __restrict__ Wbf) {
    int i = blockIdx.x * 256 + threadIdx.x;   // handles 4 positions
    int4 a = ((const int4*)aux)[i];
    ushort4 o;
    o.x = a.x >= 0 ? f2bf(w[a.x]) : (u16)0;
    o.y = a.y >= 0 ? f2bf(w[a.y]) : (u16)0;
    o.z = a.z >= 0 ? f2bf(w[a.z]) : (u16)0;
    o.w = a.w >= 0 ? f2bf(w[a.w]) : (u16)0;
    ((ushort4*)Wbf)[i] = o;
}

__global__ __launch_bounds__(256) void conv_x(const float* __restrict__ x,
                                              u16* __restrict__ xbf) {
    int i = blockIdx.x * 256 + threadIdx.x;   // handles 4 elements
    float4 v = ((const float4*)x)[i];
    ushort4 o;
    o.x = f2bf(v.x); o.y = f2bf(v.y); o.z = f2bf(v.z); o.w = f2bf(v.w);
    ((ushort4*)xbf)[i] = o;
}

// C[m][n] = sum_k A[m][k] * B[n][k] + bias[n]
// A: [BATCH][IN_F] bf16 (x), B: [OUT_F][IN_F] bf16 (W row-major = B^T layout), C f32.
__global__ __launch_bounds__(256) void gemm_bias(const u16* __restrict__ A,
                                                 const u16* __restrict__ B,
                                                 const float* __restrict__ bias,
                                                 float* __restrict__ C) {
    __shared__ u16 As[BM * BK];   // [64][64]  8 KB
    __shared__ u16 Bs[BN * BK];   // [128][64] 16 KB
    const int tid  = threadIdx.x;
    const int lane = tid & 63;
    const int wave = tid >> 6;
    const int wm   = wave >> 1;          // 2x2 wave grid, wave tile 32x64
    const int wn   = wave & 1;
    const int m0   = blockIdx.x * BM;
    const int n0   = blockIdx.y * BN;
    const int r15  = lane & 15;
    const int khi  = lane >> 4;          // 0..3

    f32x4 acc[2][4];
#pragma unroll
    for (int mi = 0; mi < 2; mi++)
#pragma unroll
        for (int nj = 0; nj < 4; nj++) acc[mi][nj] = (f32x4){0.f, 0.f, 0.f, 0.f};

    for (int kt = 0; kt < IN_F; kt += BK) {
        __syncthreads();  // previous iter's LDS reads complete before overwrite
        // stage A: 8192 B -> 2 issues/thread of 16 B
#pragma unroll
        for (int it = 0; it < 2; it++) {
            int o   = tid * 16 + it * 4096;       // byte offset in tile
            int row = o >> 7;                     // 128 B per row (BK*2)
            int ce  = (o & 127) >> 1;             // element col
            const u16* g = A + (size_t)(m0 + row) * IN_F + kt + ce;
            __builtin_amdgcn_global_load_lds((const __attribute__((address_space(1))) void*)g,
                                             (__attribute__((address_space(3))) void*)(As + (o >> 1)),
                                             16, 0, 0);
        }
        // stage B: 16384 B -> 4 issues/thread
#pragma unroll
        for (int it = 0; it < 4; it++) {
            int o   = tid * 16 + it * 4096;
            int row = o >> 7;
            int ce  = (o & 127) >> 1;
            const u16* g = B + (size_t)(n0 + row) * IN_F + kt + ce;
            __builtin_amdgcn_global_load_lds((const __attribute__((address_space(1))) void*)g,
                                             (__attribute__((address_space(3))) void*)(Bs + (o >> 1)),
                                             16, 0, 0);
        }
        __syncthreads();  // compiler drains vmcnt before barrier

#pragma unroll
        for (int ks = 0; ks < 2; ks++) {
            const int kof = ks * 32 + khi * 8;
            bf16x8 a[2], b[4];
#pragma unroll
            for (int mi = 0; mi < 2; mi++)
                a[mi] = *(const bf16x8*)&As[(wm * 32 + mi * 16 + r15) * BK + kof];
#pragma unroll
            for (int nj = 0; nj < 4; nj++)
                b[nj] = *(const bf16x8*)&Bs[(wn * 64 + nj * 16 + r15) * BK + kof];
#pragma unroll
            for (int mi = 0; mi < 2; mi++)
#pragma unroll
                for (int nj = 0; nj < 4; nj++)
                    acc[mi][nj] = __builtin_amdgcn_mfma_f32_16x16x32_bf16(a[mi], b[nj], acc[mi][nj], 0, 0, 0);
        }
    }

    // epilogue: D layout col=lane&15, row=(lane>>4)*4+j
#pragma unroll
    for (int nj = 0; nj < 4; nj++) {
        int colg = n0 + wn * 64 + nj * 16 + r15;
        float bv = bias[colg];
#pragma unroll
        for (int mi = 0; mi < 2; mi++) {
#pragma unroll
            for (int j = 0; j < 4; j++) {
                int rowg = m0 + wm * 32 + mi * 16 + khi * 4 + j;
                C[(size_t)rowg * OUT_F + colg] = acc[mi][nj][j] + bv;
            }
        }
    }
}

extern "C" void kernel_launch(void* const* d_in, const int* in_sizes, int n_in,
                              void* d_out, int out_size, void* d_ws, size_t ws_size,
                              hipStream_t stream) {
    const float* x    = (const float*)d_in[0];
    const float* w1d  = (const float*)d_in[1];
    const float* bias = (const float*)d_in[2];
    const int*   row  = (const int*)d_in[3];
    const int*   col  = (const int*)d_in[4];
    const int nnz = in_sizes[1];

    char* ws  = (char*)d_ws;
    int*  aux = (int*)ws;                               // 64 MB
    u16*  Wbf = (u16*)(ws + ((size_t)64 << 20));        // 32 MB
    u16*  xbf = (u16*)(ws + ((size_t)96 << 20));        // 4 MB
    float* y  = (float*)d_out;

    hipMemsetAsync(aux, 0xFF, (size_t)OUT_F * IN_F * sizeof(int), stream);  // aux = -1

    scatter_max<<<(nnz + 255) / 256, 256, 0, stream>>>(row, col, aux, nnz);
    fill_w<<<(OUT_F * IN_F / 4) / 256, 256, 0, stream>>>(aux, w1d, Wbf);
    conv_x<<<(BATCH * IN_F / 4) / 256, 256, 0, stream>>>(x, xbf);
    gemm_bias<<<dim3(BATCH / BM, OUT_F / BN), 256, 0, stream>>>(xbf, Wbf, bias, y);
}

// Round 2
// 163.445 us; speedup vs baseline: 1.0746x; 1.0746x over previous
//
#include <hip/hip_runtime.h>
#include <hip/hip_bf16.h>

typedef unsigned short u16;
typedef __attribute__((ext_vector_type(4))) float f32x4;
typedef __attribute__((ext_vector_type(8))) short bf16x8;

#define IN_F   4096
#define OUT_F  4096
#define BATCH  512

#define BM 64
#define BN 128
#define BK 64
#define KSPLIT 4
#define KC (IN_F / KSPLIT)      // 1024
#define NSTEPS (KC / BK)        // 16

__device__ inline u16 f2bf(float f) {
    __hip_bfloat16 h = __float2bfloat16(f);   // RNE
    u16 u; __builtin_memcpy(&u, &h, 2); return u;
}

// Pass 1: last-write-wins index resolution. aux pre-set to -1 (memset 0xFF).
// 8 entries per thread -> 8 atomics in flight (latency-bound before: 1/thread).
__global__ __launch_bounds__(256) void scatter_max(const int* __restrict__ row,
                                                   const int* __restrict__ col,
                                                   int* __restrict__ aux, int nnz) {
    int t = blockIdx.x * 256 + threadIdx.x;
    int base = t * 8;
    if (base + 8 <= nnz) {
#pragma unroll
        for (int j = 0; j < 2; j++) {
            int4 r = ((const int4*)row)[t * 2 + j];
            int4 c = ((const int4*)col)[t * 2 + j];
            int i0 = base + j * 4;
            atomicMax(&aux[r.x * IN_F + c.x], i0 + 0);
            atomicMax(&aux[r.y * IN_F + c.y], i0 + 1);
            atomicMax(&aux[r.z * IN_F + c.z], i0 + 2);
            atomicMax(&aux[r.w * IN_F + c.w], i0 + 3);
        }
    } else if (base < nnz) {
        for (int i = base; i < nnz; i++)
            atomicMax(&aux[row[i] * IN_F + col[i]], i);
    }
}

// Pass 2: build dense bf16 W (zero-fill fused with scatter resolution).
__global__ __launch_bounds__(256) void fill_w(const int* __restrict__ aux,
                                              const float* __restrict__ w,
                                              u16* __restrict__ Wbf) {
    int i = blockIdx.x * 256 + threadIdx.x;   // handles 4 positions
    int4 a = ((const int4*)aux)[i];
    ushort4 o;
    o.x = a.x >= 0 ? f2bf(w[a.x]) : (u16)0;
    o.y = a.y >= 0 ? f2bf(w[a.y]) : (u16)0;
    o.z = a.z >= 0 ? f2bf(w[a.z]) : (u16)0;
    o.w = a.w >= 0 ? f2bf(w[a.w]) : (u16)0;
    ((ushort4*)Wbf)[i] = o;
}

__global__ __launch_bounds__(256) void conv_x(const float* __restrict__ x,
                                              u16* __restrict__ xbf) {
    int i = blockIdx.x * 256 + threadIdx.x;   // handles 4 elements
    float4 v = ((const float4*)x)[i];
    ushort4 o;
    o.x = f2bf(v.x); o.y = f2bf(v.y); o.z = f2bf(v.z); o.w = f2bf(v.w);
    ((ushort4*)xbf)[i] = o;
}

// Partial GEMM over one K-chunk: part[kc][m][n] = sum_{k in chunk} A[m][k]*B[n][k]
// Block swizzle clusters the 8 M-blocks sharing one (n,kc) B-panel onto ONE XCD
// (assumes hw xcd = linear_block_id % 8) so the panel is L2-resident after first fetch.
__global__ __launch_bounds__(256) void gemm_part(const u16* __restrict__ A,
                                                 const u16* __restrict__ B,
                                                 float* __restrict__ part) {
    __shared__ u16 As[2][BM * BK];   // 2 x 8 KB
    __shared__ u16 Bs[2][BN * BK];   // 2 x 16 KB
    const int L    = blockIdx.x;
    const int xcd  = L & 7;
    const int slot = L >> 3;
    const int m    = slot & 7;                 // 8 M-blocks
    const int g    = xcd + ((slot >> 3) << 3); // group id 0..127 -> (n, kc); g%8==xcd
    const int n    = g & 31;                   // 32 N-blocks
    const int kc   = g >> 5;                   // 4 K-chunks
    const int m0   = m * BM;
    const int n0   = n * BN;
    const int kt0  = kc * KC;

    const int tid  = threadIdx.x;
    const int lane = tid & 63;
    const int wave = tid >> 6;
    const int wm   = wave >> 1;          // 2x2 wave grid, wave tile 32x64
    const int wn   = wave & 1;
    const int r15  = lane & 15;
    const int khi  = lane >> 4;          // 0..3

    f32x4 acc[2][4];
#pragma unroll
    for (int mi = 0; mi < 2; mi++)
#pragma unroll
        for (int nj = 0; nj < 4; nj++) acc[mi][nj] = (f32x4){0.f, 0.f, 0.f, 0.f};

    // precompute staging offsets
    const int so  = tid * 16;            // byte offset within a 4096B slab

#define STAGE(buf, kt)                                                                     \
    do {                                                                                   \
        _Pragma("unroll")                                                                  \
        for (int it = 0; it < 2; it++) {                                                   \
            int o = so + it * 4096;                                                        \
            int rr = o >> 7, ce = (o & 127) >> 1;                                          \
            const u16* gptr = A + (size_t)(m0 + rr) * IN_F + (kt) + ce;                    \
            __builtin_amdgcn_global_load_lds(                                              \
                (const __attribute__((address_space(1))) void*)gptr,                       \
                (__attribute__((address_space(3))) void*)(&As[buf][0] + (o >> 1)),         \
                16, 0, 0);                                                                 \
        }                                                                                  \
        _Pragma("unroll")                                                                  \
        for (int it = 0; it < 4; it++) {                                                   \
            int o = so + it * 4096;                                                        \
            int rr = o >> 7, ce = (o & 127) >> 1;                                          \
            const u16* gptr = B + (size_t)(n0 + rr) * IN_F + (kt) + ce;                    \
            __builtin_amdgcn_global_load_lds(                                              \
                (const __attribute__((address_space(1))) void*)gptr,                       \
                (__attribute__((address_space(3))) void*)(&Bs[buf][0] + (o >> 1)),         \
                16, 0, 0);                                                                 \
        }                                                                                  \
    } while (0)

    STAGE(0, kt0);
    __syncthreads();   // drains vmcnt -> buf0 ready

    for (int t = 0; t < NSTEPS; ++t) {
        const int cur = t & 1;
        if (t + 1 < NSTEPS) STAGE(cur ^ 1, kt0 + (t + 1) * BK);  // prefetch next, in flight under compute

#pragma unroll
        for (int ks = 0; ks < 2; ks++) {
            const int kof = ks * 32 + khi * 8;
            bf16x8 a[2], b[4];
#pragma unroll
            for (int mi = 0; mi < 2; mi++)
                a[mi] = *(const bf16x8*)&As[cur][(wm * 32 + mi * 16 + r15) * BK + kof];
#pragma unroll
            for (int nj = 0; nj < 4; nj++)
                b[nj] = *(const bf16x8*)&Bs[cur][(wn * 64 + nj * 16 + r15) * BK + kof];
#pragma unroll
            for (int mi = 0; mi < 2; mi++)
#pragma unroll
                for (int nj = 0; nj < 4; nj++)
                    acc[mi][nj] = __builtin_amdgcn_mfma_f32_16x16x32_bf16(a[mi], b[nj], acc[mi][nj], 0, 0, 0);
        }
        __syncthreads();   // drains prefetch loads; guards buf reuse next iter
    }
#undef STAGE

    float* P = part + (size_t)kc * BATCH * OUT_F;
#pragma unroll
    for (int nj = 0; nj < 4; nj++) {
        int colg = n0 + wn * 64 + nj * 16 + r15;
#pragma unroll
        for (int mi = 0; mi < 2; mi++) {
#pragma unroll
            for (int j = 0; j < 4; j++) {
                int rowg = m0 + wm * 32 + mi * 16 + khi * 4 + j;
                P[(size_t)rowg * OUT_F + colg] = acc[mi][nj][j];
            }
        }
    }
}

// y = sum_k part[k] + bias
__global__ __launch_bounds__(256) void reduce_bias(const float* __restrict__ part,
                                                   const float* __restrict__ bias,
                                                   float* __restrict__ y) {
    int i = blockIdx.x * 256 + threadIdx.x;          // f32x4 index
    const size_t STRIDE = (size_t)BATCH * OUT_F / 4; // in f32x4
    f32x4 s = ((const f32x4*)part)[i];
#pragma unroll
    for (int k = 1; k < KSPLIT; k++) s += ((const f32x4*)part)[i + k * STRIDE];
    int col4 = (i * 4) & (OUT_F - 1);
    f32x4 b = *(const f32x4*)&bias[col4];
    ((f32x4*)y)[i] = s + b;
}

extern "C" void kernel_launch(void* const* d_in, const int* in_sizes, int n_in,
                              void* d_out, int out_size, void* d_ws, size_t ws_size,
                              hipStream_t stream) {
    const float* x    = (const float*)d_in[0];
    const float* w1d  = (const float*)d_in[1];
    const float* bias = (const float*)d_in[2];
    const int*   row  = (const int*)d_in[3];
    const int*   col  = (const int*)d_in[4];
    const int nnz = in_sizes[1];

    char*  ws   = (char*)d_ws;
    int*   aux  = (int*)ws;                            // 64 MB [0,64)
    float* part = (float*)ws;                          // 32 MB [0,32) — overlays aux (dead after fill_w)
    u16*   Wbf  = (u16*)(ws + ((size_t)64 << 20));     // 32 MB
    u16*   xbf  = (u16*)(ws + ((size_t)96 << 20));     // 4 MB
    float* y    = (float*)d_out;

    hipMemsetAsync(aux, 0xFF, (size_t)OUT_F * IN_F * sizeof(int), stream);  // aux = -1

    int sthreads = (nnz + 7) / 8;
    scatter_max<<<(sthreads + 255) / 256, 256, 0, stream>>>(row, col, aux, nnz);
    fill_w<<<(OUT_F * IN_F / 4) / 256, 256, 0, stream>>>(aux, w1d, Wbf);
    conv_x<<<(BATCH * IN_F / 4) / 256, 256, 0, stream>>>(x, xbf);
    gemm_part<<<8 * 32 * KSPLIT, 256, 0, stream>>>(xbf, Wbf, part);
    reduce_bias<<<(BATCH * OUT_F / 4) / 256, 256, 0, stream>>>(part, bias, y);
}